// Round 1
// baseline (1326.238 us; speedup 1.0000x reference)
//
#include <hip/hip_runtime.h>
#include <hip/hip_fp16.h>
#include <stdint.h>

// ---------------------------------------------------------------------------
// Seq2SeqARDiffusion on MI355X.
// Phases (all launched on `stream`, stream-ordered):
//   k_prep_xh : build packed-fp16 [x_hist|emb] inputs for LSTM0, layout [t][b][12 u32]
//   k_prep_w  : pack LSTM0/LSTM1/W2 weights to fp16 (+ bias sums)
//   k_lstm0   : persistent LSTM layer 0, 256 WGs x 512 thr, 4 batch/WG, weights in VGPRs
//   k_lstm1   : persistent LSTM layer 1 -> enc_out, same structure
//   k_diff    : persistent AR-diffusion, 1024 WGs x 128 thr, 1 batch/WG
// ---------------------------------------------------------------------------

typedef __attribute__((ext_vector_type(2))) _Float16 half2_t;

#define DEV __device__ __forceinline__

DEV float fdot2(uint32_t a, uint32_t b, float c) {
#if __has_builtin(__builtin_amdgcn_fdot2)
  return __builtin_amdgcn_fdot2(__builtin_bit_cast(half2_t, a),
                                __builtin_bit_cast(half2_t, b), c, false);
#else
  half2_t ha = __builtin_bit_cast(half2_t, a);
  half2_t hb = __builtin_bit_cast(half2_t, b);
  return c + (float)ha.x * (float)hb.x + (float)ha.y * (float)hb.y;
#endif
}

DEV uint32_t pack2f(float a, float b) {
  __half ha = __float2half_rn(a), hb = __float2half_rn(b);
  return (uint32_t)__half_as_ushort(ha) | ((uint32_t)__half_as_ushort(hb) << 16);
}

DEV float sigm(float x) { return 1.0f / (1.0f + expf(-x)); }

// ---------------- workspace layout (bytes) ----------------
static constexpr size_t OFF_XH  = 0;                       // 96*1024*12 u32 = 4,718,592 B
static constexpr size_t OFF_W0  = 4718592;                 // 512*76 u32     = 155,648 B
static constexpr size_t OFF_BS0 = OFF_W0  + 155648;        // 512 f32
static constexpr size_t OFF_W1L = OFF_BS0 + 2048;          // 512*128 u32    = 262,144 B
static constexpr size_t OFF_BS1 = OFF_W1L + 262144;        // 512 f32
static constexpr size_t OFF_W2P = OFF_BS1 + 2048;          // 128*64 u32     = 32,768 B
static constexpr size_t OFF_ENC = OFF_W2P + 32768;         // 1024*128 f32   = 524,288 B
static constexpr size_t OFF_YS0 = OFF_ENC + 524288;        // 96*1024*128 half = 25,165,824 B
// total ~30.9 MB

// ---------------- prep: pack [x_hist | emb] as fp16 pairs ----------------
__global__ void k_prep_xh(const float* __restrict__ xh, const int* __restrict__ tix,
                          const float* __restrict__ temb, uint32_t* __restrict__ out) {
  int idx = blockIdx.x * 256 + threadIdx.x;             // 96*1024*12 total
  if (idx >= 96 * 1024 * 12) return;
  int m = idx % 12;
  int tb = idx / 12;
  int b = tb & 1023, t = tb >> 10;
  int k0 = 2 * m, k1 = k0 + 1;
  float v0 = (k0 < 8) ? xh[(b * 96 + t) * 8 + k0] : temb[tix[b] * 16 + (k0 - 8)];
  float v1 = (k1 < 8) ? xh[(b * 96 + t) * 8 + k1] : temb[tix[b] * 16 + (k1 - 8)];
  out[idx] = pack2f(v0, v1);
}

// ---------------- prep: pack weights fp16 ----------------
__global__ void k_prep_w(const float* __restrict__ Wih0, const float* __restrict__ Whh0,
                         const float* __restrict__ bih0, const float* __restrict__ bhh0,
                         const float* __restrict__ Wih1, const float* __restrict__ Whh1,
                         const float* __restrict__ bih1, const float* __restrict__ bhh1,
                         const float* __restrict__ W2,
                         uint32_t* __restrict__ w0p, uint32_t* __restrict__ w1p,
                         uint32_t* __restrict__ w2p, float* __restrict__ bs0,
                         float* __restrict__ bs1) {
  int idx = blockIdx.x * 256 + threadIdx.x;
  if (idx < 38912) {                       // W0: rows [Wih0 | Whh0], 512 x 76 u32
    int g = idx / 76, m = idx % 76;
    int k0 = 2 * m, k1 = k0 + 1;
    float a = (k0 < 24) ? Wih0[g * 24 + k0] : Whh0[g * 128 + k0 - 24];
    float b = (k1 < 24) ? Wih0[g * 24 + k1] : Whh0[g * 128 + k1 - 24];
    w0p[idx] = pack2f(a, b);
  } else if (idx < 104448) {               // W1L: rows [Wih1 | Whh1], 512 x 128 u32
    int i = idx - 38912;
    int g = i >> 7, m = i & 127;
    int k0 = 2 * m, k1 = k0 + 1;
    float a = (k0 < 128) ? Wih1[g * 128 + k0] : Whh1[g * 128 + k0 - 128];
    float b = (k1 < 128) ? Wih1[g * 128 + k1] : Whh1[g * 128 + k1 - 128];
    w1p[i] = pack2f(a, b);
  } else if (idx < 112640) {               // W2: 128 x 64 u32 (row-major pairs)
    int i = idx - 104448;
    w2p[i] = pack2f(W2[2 * i], W2[2 * i + 1]);
  } else if (idx < 113152) {
    int i = idx - 112640;
    bs0[i] = bih0[i] + bhh0[i];
  } else if (idx < 113664) {
    int i = idx - 113152;
    bs1[i] = bih1[i] + bhh1[i];
  }
}

// ---------------- LSTM layer 0 (persistent; 4 batch/WG) ----------------
// thread: j = tid&127 (hidden unit), kh = (tid>>7)&1 (k half), bh = tid>>8 (batch pair)
// each thread owns fp16 rows {j,128+j,256+j,384+j} x 76-half k-slice in VGPRs.
__global__ __launch_bounds__(512) void k_lstm0(const uint32_t* __restrict__ xh16,
                                               const uint32_t* __restrict__ w0p,
                                               const float* __restrict__ bs0,
                                               __half* __restrict__ ys0) {
  __shared__ __align__(16) uint32_t in_u[4][80];  // per b: [x(24) | h(128)] halfs (+pad)
  __shared__ float4 part[128][2][2];              // [j][bh][bi] partial gates from kh=1
  const int tid = threadIdx.x;
  const int j = tid & 127, kh = (tid >> 7) & 1, bh = tid >> 8;
  const int bbase = blockIdx.x * 4;

  uint32_t wreg[4][38];
#pragma unroll
  for (int q = 0; q < 4; q++) {
    const uint32_t* src = w0p + (j + 128 * q) * 76 + kh * 38;
#pragma unroll
    for (int m = 0; m < 38; m++) wreg[q][m] = src[m];
  }
  float bsv[4] = {0.f, 0.f, 0.f, 0.f};
  if (kh == 0) {
#pragma unroll
    for (int q = 0; q < 4; q++) bsv[q] = bs0[j + 128 * q];
  }
  for (int z = tid; z < 320; z += 512) {
    int bb = z / 80, m = z % 80;
    if (m >= 12) in_u[bb][m] = 0u;   // zero h region (+pad)
  }
  float cst[2] = {0.f, 0.f};

  for (int t = 0; t < 96; t++) {
    if (tid >= 128 && tid < 176) {   // stage x_t (48 u32), kh=1/bh=0 threads
      int e = tid - 128;
      int bl = e / 12, m = e % 12;
      in_u[bl][m] = xh16[(t * 1024 + bbase + bl) * 12 + m];
    }
    __syncthreads();
    float acc[4][2];
#pragma unroll
    for (int q = 0; q < 4; q++) { acc[q][0] = 0.f; acc[q][1] = 0.f; }
#pragma unroll
    for (int bi = 0; bi < 2; bi++) {
      const uint32_t* iu = &in_u[bh * 2 + bi][kh * 38];
#pragma unroll
      for (int m = 0; m < 38; m++) {
        uint32_t u = iu[m];
        acc[0][bi] = fdot2(wreg[0][m], u, acc[0][bi]);
        acc[1][bi] = fdot2(wreg[1][m], u, acc[1][bi]);
        acc[2][bi] = fdot2(wreg[2][m], u, acc[2][bi]);
        acc[3][bi] = fdot2(wreg[3][m], u, acc[3][bi]);
      }
    }
    if (kh == 1) {
      part[j][bh][0] = make_float4(acc[0][0], acc[1][0], acc[2][0], acc[3][0]);
      part[j][bh][1] = make_float4(acc[0][1], acc[1][1], acc[2][1], acc[3][1]);
    }
    __syncthreads();
    if (kh == 0) {
#pragma unroll
      for (int bi = 0; bi < 2; bi++) {
        int b = bh * 2 + bi;
        float4 p = part[j][bh][bi];
        float gi = acc[0][bi] + p.x + bsv[0];
        float gf = acc[1][bi] + p.y + bsv[1];
        float gg = acc[2][bi] + p.z + bsv[2];
        float go = acc[3][bi] + p.w + bsv[3];
        float c = sigm(gf) * cst[bi] + sigm(gi) * tanhf(gg);
        cst[bi] = c;
        float h = sigm(go) * tanhf(c);
        __half hh = __float2half_rn(h);
        ((__half*)&in_u[b][0])[24 + j] = hh;                 // h for next step
        ys0[(t * 1024 + bbase + b) * 128 + j] = hh;          // layer-1 input
      }
    }
  }
}

// ---------------- LSTM layer 1 (persistent; 4 batch/WG) ----------------
// thread: j = tid&127, kq = tid>>7 (k quarter of 256). Owns 4 rows x 32 u32 slice.
__global__ __launch_bounds__(512) void k_lstm1(const uint32_t* __restrict__ ys0u,
                                               const uint32_t* __restrict__ w1p,
                                               const float* __restrict__ bs1,
                                               float* __restrict__ enc) {
  __shared__ __align__(16) uint32_t in_u[4][128];  // per b: [ys0_t(128) | h(128)] halfs
  __shared__ float4 part[3][128][4];               // [kq-1][j][b] partial gates
  const int tid = threadIdx.x;
  const int j = tid & 127, kq = tid >> 7;
  const int bbase = blockIdx.x * 4;

  uint32_t wreg[4][32];
#pragma unroll
  for (int q = 0; q < 4; q++) {
    const uint32_t* src = w1p + (j + 128 * q) * 128 + kq * 32;
#pragma unroll
    for (int m = 0; m < 32; m++) wreg[q][m] = src[m];
  }
  float bsv[4] = {0.f, 0.f, 0.f, 0.f};
  float cst[4] = {0.f, 0.f, 0.f, 0.f};
  if (kq == 0) {
#pragma unroll
    for (int q = 0; q < 4; q++) bsv[q] = bs1[j + 128 * q];
  }
  for (int z = tid; z < 256; z += 512) {
    int bb = z >> 6, m = z & 63;
    in_u[bb][64 + m] = 0u;   // zero h region
  }

  for (int t = 0; t < 96; t++) {
    if (tid >= 256) {        // stage ys0[t] (256 u32), kq=2,3 threads
      int e = tid - 256;
      int bl = e >> 6, m = e & 63;
      in_u[bl][m] = ys0u[(t * 1024 + bbase + bl) * 64 + m];
    }
    __syncthreads();
    float acc[4][4];
#pragma unroll
    for (int q = 0; q < 4; q++)
#pragma unroll
      for (int b = 0; b < 4; b++) acc[q][b] = 0.f;
#pragma unroll
    for (int b = 0; b < 4; b++) {
      const uint32_t* iu = &in_u[b][kq * 32];
#pragma unroll
      for (int m = 0; m < 32; m++) {
        uint32_t u = iu[m];
        acc[0][b] = fdot2(wreg[0][m], u, acc[0][b]);
        acc[1][b] = fdot2(wreg[1][m], u, acc[1][b]);
        acc[2][b] = fdot2(wreg[2][m], u, acc[2][b]);
        acc[3][b] = fdot2(wreg[3][m], u, acc[3][b]);
      }
    }
    if (kq > 0) {
#pragma unroll
      for (int b = 0; b < 4; b++)
        part[kq - 1][j][b] = make_float4(acc[0][b], acc[1][b], acc[2][b], acc[3][b]);
    }
    __syncthreads();
    if (kq == 0) {
#pragma unroll
      for (int b = 0; b < 4; b++) {
        float4 p0 = part[0][j][b], p1 = part[1][j][b], p2 = part[2][j][b];
        float gi = acc[0][b] + p0.x + p1.x + p2.x + bsv[0];
        float gf = acc[1][b] + p0.y + p1.y + p2.y + bsv[1];
        float gg = acc[2][b] + p0.z + p1.z + p2.z + bsv[2];
        float go = acc[3][b] + p0.w + p1.w + p2.w + bsv[3];
        float c = sigm(gf) * cst[b] + sigm(gi) * tanhf(gg);
        cst[b] = c;
        float h = sigm(go) * tanhf(c);
        ((__half*)&in_u[b][0])[128 + j] = __float2half_rn(h);
        if (t == 95) enc[(bbase + b) * 128 + j] = h;   // enc_out fp32
      }
    }
  }
}

// ---------------- AR diffusion (persistent; 1 batch/WG, 128 thr) ----------------
// W1 columns: [0:128) enc | [128:134) exo | [134:150) emb | 150 prev_y | 151 y |
//             [152:168) t_e | [168:184) h_e
__global__ __launch_bounds__(128) void k_diff(
    const float* __restrict__ xfut, const float* __restrict__ y0,
    const int* __restrict__ tix, const float* __restrict__ noise,
    const float* __restrict__ temb, const float* __restrict__ W1,
    const float* __restrict__ b1, const float* __restrict__ b2,
    const float* __restrict__ W3, const float* __restrict__ b3,
    const uint32_t* __restrict__ w2p, const float* __restrict__ enc,
    float* __restrict__ out) {
  __shared__ float teL[100][16];
  __shared__ __align__(16) __half tprojH[100][128];
  __shared__ float encL[128];
  __shared__ __align__(16) uint32_t h1u[64];   // h1 as 128 fp16
  __shared__ float csub[100], cdiv[100];
  __shared__ float partials[2];
  const int j = threadIdx.x;
  const int b = blockIdx.x;

  uint32_t w2r[64];                             // W2 row j, fp16 pairs, in VGPRs
#pragma unroll
  for (int m = 0; m < 64; m++) w2r[m] = w2p[j * 64 + m];
  const float* w1row = W1 + j * 184;
  float w1y = w1row[151], w3v = W3[j], b2v = b2[j], b1v = b1[j], b3v = b3[0];
  float wte[16], whe[16];
#pragma unroll
  for (int i = 0; i < 16; i++) { wte[i] = w1row[152 + i]; whe[i] = w1row[168 + i]; }
  encL[j] = enc[b * 128 + j];

  // sinusoidal table te[t][0:8)=cos(t*f_i), [8:16)=sin(t*f_i)
  for (int p = j; p < 1600; p += 128) {
    int tt = p >> 4, i = p & 15;
    float f = expf(-logf(10000.f) * (float)(i & 7) / 8.f);
    float a = (float)tt * f;
    teL[tt][i] = (i < 8) ? cosf(a) : sinf(a);
  }
  // diffusion coefficients: y' = (y - csub[t]*eps) * cdiv[t]
  if (j < 100) {
    float ab = 1.f, beta = 0.f;
    for (int i = 0; i <= j; i++) {
      beta = 1e-4f + (0.02f - 1e-4f) * (float)i / 99.f;
      ab *= (1.f - beta);
    }
    if (j == 0) {
      csub[0] = sqrtf(1.f - ab);
      cdiv[0] = 1.f / (sqrtf(ab) + 1e-8f);
    } else {
      csub[j] = beta / (sqrtf(1.f - ab) + 1e-8f);
      cdiv[j] = 1.f / (sqrtf(1.f - beta) + 1e-8f);
    }
  }
  __syncthreads();
  // tproj[t][j] = W1_te(row j) . te[t]  (thread j writes its own column)
  for (int tt = 0; tt < 100; tt++) {
    float s = 0.f;
#pragma unroll
    for (int i = 0; i < 16; i++) s += wte[i] * teL[tt][i];
    tprojH[tt][j] = __float2half_rn(s);
  }
  float prev_y = y0[b];
  float embr[16];
#pragma unroll
  for (int i = 0; i < 16; i++) embr[i] = temb[tix[b] * 16 + i];
  __syncthreads();

  for (int s = 0; s < 8; s++) {
    // base = b1 + W1_cond . cond + W1_he . h_e(s)   (constant over the 100 t-steps)
    float base = b1v;
#pragma unroll 8
    for (int k = 0; k < 128; k++) base += w1row[k] * encL[k];
#pragma unroll
    for (int i = 0; i < 6; i++) base += w1row[128 + i] * xfut[(b * 8 + s) * 6 + i];
#pragma unroll
    for (int i = 0; i < 16; i++) base += w1row[134 + i] * embr[i];
    base += w1row[150] * prev_y;
#pragma unroll
    for (int i = 0; i < 16; i++) base += whe[i] * teL[s][i];

    float y = noise[s * 1024 + b];
    for (int t = 99; t >= 0; t--) {
      float h1 = base + y * w1y + __half2float(tprojH[t][j]);
      h1 = fmaxf(h1, 0.f);
      ((__half*)h1u)[j] = __float2half_rn(h1);
      __syncthreads();
      float a2 = 0.f;
      const uint4* hv = (const uint4*)h1u;
#pragma unroll
      for (int mm = 0; mm < 16; mm++) {       // 128x128 GEMV row j, wave-uniform reads
        uint4 u = hv[mm];
        a2 = fdot2(w2r[4 * mm + 0], u.x, a2);
        a2 = fdot2(w2r[4 * mm + 1], u.y, a2);
        a2 = fdot2(w2r[4 * mm + 2], u.z, a2);
        a2 = fdot2(w2r[4 * mm + 3], u.w, a2);
      }
      float h2 = fmaxf(a2 + b2v, 0.f);
      float contrib = w3v * h2;
#pragma unroll
      for (int off = 1; off < 64; off <<= 1) contrib += __shfl_xor(contrib, off, 64);
      if ((j & 63) == 0) partials[j >> 6] = contrib;
      __syncthreads();
      float eps = partials[0] + partials[1] + b3v;
      y = (y - csub[t] * eps) * cdiv[t];
    }
    if (j == 0) out[b * 8 + s] = y;
    prev_y = y;
  }
}

// ---------------------------------------------------------------------------
extern "C" void kernel_launch(void* const* d_in, const int* in_sizes, int n_in,
                              void* d_out, int out_size, void* d_ws, size_t ws_size,
                              hipStream_t stream) {
  const float* x_hist    = (const float*)d_in[0];
  const float* x_future  = (const float*)d_in[1];
  const float* y0        = (const float*)d_in[2];
  const int*   turb_idx  = (const int*)d_in[3];
  // d_in[4] = pred_steps (=8, fixed by shapes)
  const float* init_noise = (const float*)d_in[5];
  const float* turb_emb  = (const float*)d_in[6];
  const float* W_ih0     = (const float*)d_in[7];
  const float* W_hh0     = (const float*)d_in[8];
  const float* b_ih0     = (const float*)d_in[9];
  const float* b_hh0     = (const float*)d_in[10];
  const float* W_ih1     = (const float*)d_in[11];
  const float* W_hh1     = (const float*)d_in[12];
  const float* b_ih1     = (const float*)d_in[13];
  const float* b_hh1     = (const float*)d_in[14];
  const float* W1        = (const float*)d_in[15];
  const float* b1        = (const float*)d_in[16];
  const float* W2        = (const float*)d_in[17];
  const float* b2        = (const float*)d_in[18];
  const float* W3        = (const float*)d_in[19];
  const float* b3        = (const float*)d_in[20];

  char* ws = (char*)d_ws;
  uint32_t* xh16 = (uint32_t*)(ws + OFF_XH);
  uint32_t* w0p  = (uint32_t*)(ws + OFF_W0);
  float*    bs0  = (float*)(ws + OFF_BS0);
  uint32_t* w1p  = (uint32_t*)(ws + OFF_W1L);
  float*    bs1  = (float*)(ws + OFF_BS1);
  uint32_t* w2p  = (uint32_t*)(ws + OFF_W2P);
  float*    encf = (float*)(ws + OFF_ENC);
  __half*   ys0h = (__half*)(ws + OFF_YS0);

  k_prep_xh<<<4608, 256, 0, stream>>>(x_hist, turb_idx, turb_emb, xh16);
  k_prep_w<<<444, 256, 0, stream>>>(W_ih0, W_hh0, b_ih0, b_hh0,
                                    W_ih1, W_hh1, b_ih1, b_hh1,
                                    W2, w0p, w1p, w2p, bs0, bs1);
  k_lstm0<<<256, 512, 0, stream>>>(xh16, w0p, bs0, ys0h);
  k_lstm1<<<256, 512, 0, stream>>>((const uint32_t*)ys0h, w1p, bs1, encf);
  k_diff<<<1024, 128, 0, stream>>>(x_future, y0, turb_idx, init_noise, turb_emb,
                                   W1, b1, b2, W3, b3, w2p, encf, (float*)d_out);
}